// Round 10
// baseline (766.615 us; speedup 1.0000x reference)
//
#include <hip/hip_runtime.h>
#include <math.h>

#define TPB 256

constexpr int Bn = 8, Cn = 3, Hn = 1024, Wn = 512;
constexpr long long HWn  = (long long)Hn * Wn;      // 524288 = 2^19
constexpr long long CHWn = (long long)Cn * HWn;     // 1572864
constexpr float INV_NTOT = 1.0f / (float)(Cn * Hn * Wn);
constexpr float EPS10 = 4.5399929762484854e-05f;    // exp(-10)
constexpr float S3 = 0.86602540378443864676f;       // sqrt(3)/2

#define SWZ(x) ((x) + ((x) >> 3))

// ---------------------------------------------------------------------------
// Forward FFT along W (512) for all 3 channels of one (b,h) row, fused with
// the 3-point forward C-DFT. Reads real x, writes complex F (full W+C pass).
// ---------------------------------------------------------------------------
__global__ __launch_bounds__(TPB) void k_fft_wc_fwd(const float* __restrict__ x,
                                                    float2* __restrict__ F) {
    __shared__ float sre[3][576], sim[3][576], twc[256], tws[256];
    int rb = blockIdx.x;                    // b*H + h
    int b = rb >> 10, h = rb & 1023;
    const float* xb = x + (long long)b * CHWn + (long long)h * Wn;
    float2* Fb = F + (long long)b * CHWn + (long long)h * Wn;
    int t = threadIdx.x;

    {   float s, c;
        sincospif(-2.0f * (float)t / (float)Wn, &s, &c);
        twc[t] = c; tws[t] = s; }
    for (int i = t; i < Wn; i += TPB) {
        int j = SWZ(__brev((unsigned)i) >> (32 - 9));
        #pragma unroll
        for (int ch = 0; ch < 3; ch++) {
            sre[ch][j] = xb[ch * HWn + i];
            sim[ch][j] = 0.0f;
        }
    }
    __syncthreads();
    #pragma unroll
    for (int st = 0; st < 9; st++) {
        int half = 1 << st;
        int blk = t >> st, j = t & (half - 1);
        int pos = (blk << (st + 1)) + j;
        float c = twc[j << (8 - st)], s = tws[j << (8 - st)];
        int p0 = SWZ(pos), p1 = SWZ(pos + half);
        #pragma unroll
        for (int ch = 0; ch < 3; ch++) {
            float ure = sre[ch][p0], uim = sim[ch][p0];
            float vre = sre[ch][p1], vim = sim[ch][p1];
            float tre = vre * c - vim * s, tim = vre * s + vim * c;
            sre[ch][p0] = ure + tre;  sim[ch][p0] = uim + tim;
            sre[ch][p1] = ure - tre;  sim[ch][p1] = uim - tim;
        }
        __syncthreads();
    }
    // forward 3-point C-DFT + store
    for (int i = t; i < Wn; i += TPB) {
        int a = SWZ(i);
        float x0 = sre[0][a], y0 = sim[0][a];
        float x1 = sre[1][a], y1 = sim[1][a];
        float x2 = sre[2][a], y2 = sim[2][a];
        float sx = x1 + x2, sy = y1 + y2, dx = x1 - x2, dy = y1 - y2;
        Fb[i]           = make_float2(x0 + sx, y0 + sy);
        Fb[HWn + i]     = make_float2(x0 - 0.5f * sx + S3 * dy, y0 - 0.5f * sy - S3 * dx);
        Fb[2 * HWn + i] = make_float2(x0 - 0.5f * sx - S3 * dy, y0 - 0.5f * sy + S3 * dx);
    }
}

// ---------------------------------------------------------------------------
// Inverse: 3-point C-inverse fused with inverse W-FFT and |.|/N -> SRabs.
// ---------------------------------------------------------------------------
__global__ __launch_bounds__(TPB) void k_ifft_wc_abs(const float2* __restrict__ F,
                                                     float* __restrict__ SRabs) {
    __shared__ float sre[3][576], sim[3][576], twc[256], tws[256];
    int rb = blockIdx.x;
    int b = rb >> 10, h = rb & 1023;
    const float2* Fb = F + (long long)b * CHWn + (long long)h * Wn;
    float* ob = SRabs + (long long)b * CHWn + (long long)h * Wn;
    int t = threadIdx.x;

    {   float s, c;
        sincospif(2.0f * (float)t / (float)Wn, &s, &c);
        twc[t] = c; tws[t] = s; }
    for (int i = t; i < Wn; i += TPB) {
        float2 z0 = Fb[i], z1 = Fb[HWn + i], z2 = Fb[2 * HWn + i];
        float sx = z1.x + z2.x, sy = z1.y + z2.y;
        float dx = z1.x - z2.x, dy = z1.y - z2.y;
        int j = SWZ(__brev((unsigned)i) >> (32 - 9));
        sre[0][j] = z0.x + sx;                 sim[0][j] = z0.y + sy;
        sre[1][j] = z0.x - 0.5f * sx - S3 * dy; sim[1][j] = z0.y - 0.5f * sy + S3 * dx;
        sre[2][j] = z0.x - 0.5f * sx + S3 * dy; sim[2][j] = z0.y - 0.5f * sy - S3 * dx;
    }
    __syncthreads();
    #pragma unroll
    for (int st = 0; st < 9; st++) {
        int half = 1 << st;
        int blk = t >> st, j = t & (half - 1);
        int pos = (blk << (st + 1)) + j;
        float c = twc[j << (8 - st)], s = tws[j << (8 - st)];
        int p0 = SWZ(pos), p1 = SWZ(pos + half);
        #pragma unroll
        for (int ch = 0; ch < 3; ch++) {
            float ure = sre[ch][p0], uim = sim[ch][p0];
            float vre = sre[ch][p1], vim = sim[ch][p1];
            float tre = vre * c - vim * s, tim = vre * s + vim * c;
            sre[ch][p0] = ure + tre;  sim[ch][p0] = uim + tim;
            sre[ch][p1] = ure - tre;  sim[ch][p1] = uim - tim;
        }
        __syncthreads();
    }
    for (int i = t; i < Wn; i += TPB) {
        int a = SWZ(i);
        #pragma unroll
        for (int ch = 0; ch < 3; ch++) {
            float re = sre[ch][a], im = sim[ch][a];
            ob[ch * HWn + i] = sqrtf(re * re + im * im) * INV_NTOT;
        }
    }
}

// ---------------------------------------------------------------------------
// FFT along H (1024), 4 w-columns per block, float4 global I/O, swizzled LDS.
// INV=0 (fwd): epilogue also writes LA = log(|F|+eps).
// INV=1 (inv): prologue applies compose G = exp(LA-AF) * z/|z| before FFT.
// ---------------------------------------------------------------------------
template <int INV>
__global__ __launch_bounds__(TPB) void k_fft_h(float2* __restrict__ F,
                                               float* __restrict__ LA,
                                               const float* __restrict__ AF) {
    constexpr int CST = 1151;
    __shared__ float sre[4 * CST], sim[4 * CST], twc[Hn / 2], tws[Hn / 2];
    int bid = blockIdx.x;
    int wt = bid & 127;            // W/4 = 128 tiles
    int bc = bid >> 7;             // b*C + c
    float4* base4 = (float4*)(F + (long long)bc * HWn);
    float* LAc = LA + (long long)bc * HWn;
    const float* AFb = AF + (long long)(bc / 3) * HWn;
    int t = threadIdx.x;

    for (int i = t; i < Hn / 2; i += TPB) {
        float s, c;
        sincospif((INV ? 2.0f : -2.0f) * (float)i / (float)Hn, &s, &c);
        twc[i] = c; tws[i] = s;
    }
    for (int i = t; i < 2048; i += TPB) {
        int h = i >> 1, l = i & 1;
        float4 v = base4[h * (Wn / 2) + wt * 2 + l];
        if (INV) {          // compose: G = exp(la-af) * z/|z|
            float2 la2 = *(const float2*)(LAc + (long long)h * Wn + wt * 4 + 2 * l);
            float2 af2 = *(const float2*)(AFb + (long long)h * Wn + wt * 4 + 2 * l);
            float m0 = expf(la2.x - af2.x);
            float r0 = sqrtf(v.x * v.x + v.y * v.y);
            if (r0 > 0.0f) { float sc = m0 / r0; v.x *= sc; v.y *= sc; }
            else           { v.x = m0; v.y = 0.0f; }
            float m1 = expf(la2.y - af2.y);
            float r1 = sqrtf(v.z * v.z + v.w * v.w);
            if (r1 > 0.0f) { float sc = m1 / r1; v.z *= sc; v.w *= sc; }
            else           { v.z = m1; v.w = 0.0f; }
        }
        int hj = __brev((unsigned)h) >> (32 - 10);
        int a = hj + (hj >> 3);
        int w0 = 2 * l;
        sre[w0 * CST + a] = v.x;        sim[w0 * CST + a] = v.y;
        sre[(w0 + 1) * CST + a] = v.z;  sim[(w0 + 1) * CST + a] = v.w;
    }
    __syncthreads();
    for (int st = 0; st < 10; st++) {
        int half = 1 << st;
        #pragma unroll
        for (int qq = 0; qq < 8; qq++) {           // 2048 butterflies / 256 thr
            int q = qq * TPB + t;
            int w = q >> 9;
            int i = q & 511;
            int blk = i >> st, j = i & (half - 1);
            int pos = (blk << (st + 1)) + j;
            int tid = j << (9 - st);
            float c = twc[tid], s = tws[tid];
            int pr = pos + half;
            int p0 = w * CST + pos + (pos >> 3);
            int p1 = w * CST + pr + (pr >> 3);
            float ure = sre[p0], uim = sim[p0];
            float vre = sre[p1], vim = sim[p1];
            float tre = vre * c - vim * s, tim = vre * s + vim * c;
            sre[p0] = ure + tre;  sim[p0] = uim + tim;
            sre[p1] = ure - tre;  sim[p1] = uim - tim;
        }
        __syncthreads();
    }
    for (int i = t; i < 2048; i += TPB) {
        int h = i >> 1, l = i & 1;
        int a = h + (h >> 3);
        int w0 = 2 * l;
        float4 v = make_float4(sre[w0 * CST + a], sim[w0 * CST + a],
                               sre[(w0 + 1) * CST + a], sim[(w0 + 1) * CST + a]);
        base4[h * (Wn / 2) + wt * 2 + l] = v;
        if (!INV) {         // full-3D amplitude is ready here -> log-amp
            float la0 = logf(sqrtf(v.x * v.x + v.y * v.y) + EPS10);
            float la1 = logf(sqrtf(v.z * v.z + v.w * v.w) + EPS10);
            *(float2*)(LAc + (long long)h * Wn + wt * 4 + 2 * l) = make_float2(la0, la1);
        }
    }
}

// ---------------------------------------------------------------------------
// 3x3 channel-summed separable conv (zero pad), 128w x 8h tile, float4 I/O.
// GAU=0: box 1/9. GAU=1: gaussian 1/16 + per-block partial sums (no atomics).
// ---------------------------------------------------------------------------
template <int GAU>
__global__ __launch_bounds__(TPB) void k_conv3x3(const float* __restrict__ src,
                                                 float* __restrict__ dst,
                                                 float* __restrict__ part) {
    __shared__ float tile[3][10][140];
    int w0 = blockIdx.x << 7;
    int h0 = blockIdx.y << 3;
    int b  = blockIdx.z;
    int t  = threadIdx.x;

    for (int i = t; i < 1020; i += TPB) {          // 3*10*34 float4 loads
        int c = i / 340, rem = i - c * 340;
        int hh = rem / 34, w4 = rem - hh * 34;
        int h  = h0 + hh - 1;
        int gw = w0 - 4 + (w4 << 2);
        float4 v = make_float4(0.f, 0.f, 0.f, 0.f);
        if ((unsigned)h < (unsigned)Hn && (unsigned)gw <= 508u)
            v = *(const float4*)(src + ((long long)(b * 3 + c)) * HWn +
                                 (long long)h * Wn + gw);
        *(float4*)&tile[c][hh][w4 << 2] = v;
    }
    __syncthreads();

    const float K = GAU ? 2.0f : 1.0f;
    const float norm = GAU ? (1.0f / 16.0f) : (1.0f / 9.0f);
    int hh = t >> 5;
    int wb = (t & 31) << 2;
    float o0 = 0.f, o1 = 0.f, o2 = 0.f, o3 = 0.f;
    #pragma unroll
    for (int c = 0; c < 3; c++)
        #pragma unroll
        for (int dh = 0; dh < 3; dh++) {
            const float* row = &tile[c][hh + dh][3 + wb];
            float a0 = row[0], a1 = row[1], a2 = row[2],
                  a3 = row[3], a4 = row[4], a5 = row[5];
            float vw = (dh == 1) ? K : 1.0f;
            o0 += vw * (a0 + K * a1 + a2);
            o1 += vw * (a1 + K * a2 + a3);
            o2 += vw * (a2 + K * a3 + a4);
            o3 += vw * (a3 + K * a4 + a5);
        }
    o0 *= norm; o1 *= norm; o2 *= norm; o3 *= norm;
    *(float4*)(dst + (long long)b * HWn + (long long)(h0 + hh) * Wn + w0 + wb)
        = make_float4(o0, o1, o2, o3);

    if (GAU) {
        float s = o0 + o1 + o2 + o3;
        #pragma unroll
        for (int o = 32; o > 0; o >>= 1) s += __shfl_down(s, o);
        __shared__ float ls[4];
        if ((t & 63) == 0) ls[t >> 6] = s;
        __syncthreads();
        if (t == 0)
            part[((long long)b << 9) + (blockIdx.y << 2) + blockIdx.x]
                = ls[0] + ls[1] + ls[2] + ls[3];
    }
}

// ---------------------------------------------------------------------------
// Reduce 512 per-block partials per batch -> mean[b].
// ---------------------------------------------------------------------------
__global__ __launch_bounds__(TPB) void k_mean_final(const float* __restrict__ part,
                                                    float* __restrict__ mean) {
    int b = blockIdx.x;
    int t = threadIdx.x;
    float s = part[(b << 9) + t] + part[(b << 9) + 256 + t];
    #pragma unroll
    for (int o = 32; o > 0; o >>= 1) s += __shfl_down(s, o);
    __shared__ float ls[4];
    if ((t & 63) == 0) ls[t >> 6] = s;
    __syncthreads();
    if (t == 0)
        mean[b] = (ls[0] + ls[1] + ls[2] + ls[3]) * (1.0f / (float)HWn);
}

// ---------------------------------------------------------------------------
// out[b,h,o] = b_out[o] + sum_{w,k} thr(SRg[b,(h+k-1)%H,w]) * w_out[o,w,k]
// 64h x 64o tile, 4x4/thread, grid 1024 (4 blocks/CU). A transposed in LDS
// (As[w][row], stride 68): a-reads are broadcast b128+b64, conflict-free.
// ---------------------------------------------------------------------------
__global__ __launch_bounds__(TPB) void k_outgemm(const float* __restrict__ SRg,
                                                 const float* __restrict__ meanv,
                                                 const float* __restrict__ w_out,
                                                 const float* __restrict__ b_out,
                                                 float* __restrict__ out) {
    __shared__ __align__(16) float As[32][68];    // [w][row 0..65]
    __shared__ __align__(16) float Bs[3][32][64];
    int o0 = blockIdx.x << 6;
    int h0 = blockIdx.y << 6;
    int b = blockIdx.z;
    int t = threadIdx.x;
    int to = t & 15, th = t >> 4;
    float meanb = meanv[b];
    const float* srb = SRg + (long long)b * HWn;

    float acc[4][4];
    #pragma unroll
    for (int i = 0; i < 4; i++)
        #pragma unroll
        for (int j = 0; j < 4; j++) acc[i][j] = 0.0f;

    for (int w0 = 0; w0 < Wn; w0 += 32) {
        // A tile: rows h0-1 .. h0+64 (wrap), 32 w cols, thresholded, transposed
        for (int i = t; i < 66 * 32; i += TPB) {
            int r = i >> 5, wc = i & 31;
            int h = (h0 - 1 + r) & (Hn - 1);
            float v = srb[(long long)h * Wn + w0 + wc];
            As[wc][r] = (v > meanb) ? v : 0.0f;
        }
        // B tile: w_out[o][w][k] -> Bs[k][w][oo]
        {
            int oo = t & 63, g = t >> 6;
            const float4* wpv = (const float4*)(w_out +
                (long long)(o0 + oo) * 1536 + (long long)w0 * 3 + g * 24);
            #pragma unroll
            for (int j2 = 0; j2 < 6; j2++) {
                float4 v4 = wpv[j2];
                int mm = j2 * 4;
                Bs[(mm) % 3][g * 8 + (mm) / 3][oo]         = v4.x;
                Bs[(mm + 1) % 3][g * 8 + (mm + 1) / 3][oo] = v4.y;
                Bs[(mm + 2) % 3][g * 8 + (mm + 2) / 3][oo] = v4.z;
                Bs[(mm + 3) % 3][g * 8 + (mm + 3) / 3][oo] = v4.w;
            }
        }
        __syncthreads();
        for (int w = 0; w < 32; w++) {
            float4 a03 = *(const float4*)&As[w][th << 2];
            float2 a45 = *(const float2*)&As[w][(th << 2) + 4];
            float a[6] = {a03.x, a03.y, a03.z, a03.w, a45.x, a45.y};
            #pragma unroll
            for (int k = 0; k < 3; k++) {
                float4 bv = *(const float4*)&Bs[k][w][to << 2];
                #pragma unroll
                for (int i2 = 0; i2 < 4; i2++) {
                    acc[i2][0] += a[i2 + k] * bv.x;
                    acc[i2][1] += a[i2 + k] * bv.y;
                    acc[i2][2] += a[i2 + k] * bv.z;
                    acc[i2][3] += a[i2 + k] * bv.w;
                }
            }
        }
        __syncthreads();
    }

    float4 bias = *(const float4*)&b_out[o0 + (to << 2)];
    #pragma unroll
    for (int i2 = 0; i2 < 4; i2++) {
        int h = h0 + (th << 2) + i2;
        float4 v = make_float4(acc[i2][0] + bias.x, acc[i2][1] + bias.y,
                               acc[i2][2] + bias.z, acc[i2][3] + bias.w);
        *(float4*)&out[((long long)b * Hn + h) * 512 + o0 + (to << 2)] = v;
    }
}

// ---------------------------------------------------------------------------
extern "C" void kernel_launch(void* const* d_in, const int* in_sizes, int n_in,
                              void* d_out, int out_size, void* d_ws, size_t ws_size,
                              hipStream_t stream) {
    (void)in_sizes; (void)n_in; (void)out_size;
    const float* x     = (const float*)d_in[0];
    const float* w_out = (const float*)d_in[1];
    const float* b_out = (const float*)d_in[2];
    float* out = (float*)d_out;

    const size_t CBUF_BYTES = (size_t)Bn * CHWn * sizeof(float2);  // 100663296
    const size_t LA_BYTES   = (size_t)Bn * CHWn * sizeof(float);   //  50331648
    const size_t AF_BYTES   = (size_t)Bn * HWn * sizeof(float);    //  16777216
    const size_t NEED = CBUF_BYTES + LA_BYTES + AF_BYTES + 64 + 4096 * sizeof(float);
    if (ws_size < NEED) return;

    char* ws = (char*)d_ws;
    float2* CBUF = (float2*)ws;
    float*  LA   = (float*)(ws + CBUF_BYTES);
    float*  AF   = (float*)(ws + CBUF_BYTES + LA_BYTES);
    float*  MEAN = (float*)(ws + CBUF_BYTES + LA_BYTES + AF_BYTES);
    float*  PART = (float*)(ws + CBUF_BYTES + LA_BYTES + AF_BYTES + 64);

    // forward: W-FFT + C-DFT fused; H-FFT writes F and LA
    k_fft_wc_fwd<<<Bn * Hn, TPB, 0, stream>>>(x, CBUF);
    k_fft_h<0><<<Bn * Cn * (Wn / 4), TPB, 0, stream>>>(CBUF, LA, nullptr);

    // spectral residual: box conv on LA -> AF
    k_conv3x3<0><<<dim3(4, 128, 8), TPB, 0, stream>>>(LA, AF, nullptr);

    // inverse: compose fused into H-inv load; C-inv + W-inv + abs fused
    k_fft_h<1><<<Bn * Cn * (Wn / 4), TPB, 0, stream>>>(CBUF, LA, AF);
    k_ifft_wc_abs<<<Bn * Hn, TPB, 0, stream>>>(CBUF, LA);   // SRabs -> LA

    // gaussian conv (+partials) -> SRg in AF; mean; output GEMM
    k_conv3x3<1><<<dim3(4, 128, 8), TPB, 0, stream>>>(LA, AF, PART);
    k_mean_final<<<8, TPB, 0, stream>>>(PART, MEAN);
    k_outgemm<<<dim3(8, 16, Bn), TPB, 0, stream>>>(AF, MEAN, w_out, b_out, out);
}

// Round 11
// 596.510 us; speedup vs baseline: 1.2852x; 1.2852x over previous
//
#include <hip/hip_runtime.h>
#include <math.h>

#define TPB 256

constexpr int Bn = 8, Cn = 3, Hn = 1024, Wn = 512;
constexpr long long HWn  = (long long)Hn * Wn;      // 524288 = 2^19
constexpr long long CHWn = (long long)Cn * HWn;     // 1572864
constexpr float INV_NTOT = 1.0f / (float)(Cn * Hn * Wn);
constexpr float EPS10 = 4.5399929762484854e-05f;    // exp(-10)
constexpr float S3 = 0.86602540378443864676f;       // sqrt(3)/2

#define SWZ(x) ((x) + ((x) >> 3))

// ---------------------------------------------------------------------------
// Forward FFT along W (512) for all 3 channels of one (b,h) row, fused with
// the 3-point forward C-DFT. Reads real x, writes complex F (full W+C pass).
// ---------------------------------------------------------------------------
__global__ __launch_bounds__(TPB) void k_fft_wc_fwd(const float* __restrict__ x,
                                                    float2* __restrict__ F) {
    __shared__ float sre[3][576], sim[3][576], twc[256], tws[256];
    int rb = blockIdx.x;                    // b*H + h
    int b = rb >> 10, h = rb & 1023;
    const float* xb = x + (long long)b * CHWn + (long long)h * Wn;
    float2* Fb = F + (long long)b * CHWn + (long long)h * Wn;
    int t = threadIdx.x;

    {   float s, c;
        sincospif(-2.0f * (float)t / (float)Wn, &s, &c);
        twc[t] = c; tws[t] = s; }
    for (int i = t; i < Wn; i += TPB) {
        int j = SWZ(__brev((unsigned)i) >> (32 - 9));
        #pragma unroll
        for (int ch = 0; ch < 3; ch++) {
            sre[ch][j] = xb[ch * HWn + i];
            sim[ch][j] = 0.0f;
        }
    }
    __syncthreads();
    #pragma unroll
    for (int st = 0; st < 9; st++) {
        int half = 1 << st;
        int blk = t >> st, j = t & (half - 1);
        int pos = (blk << (st + 1)) + j;
        float c = twc[j << (8 - st)], s = tws[j << (8 - st)];
        int p0 = SWZ(pos), p1 = SWZ(pos + half);
        #pragma unroll
        for (int ch = 0; ch < 3; ch++) {
            float ure = sre[ch][p0], uim = sim[ch][p0];
            float vre = sre[ch][p1], vim = sim[ch][p1];
            float tre = vre * c - vim * s, tim = vre * s + vim * c;
            sre[ch][p0] = ure + tre;  sim[ch][p0] = uim + tim;
            sre[ch][p1] = ure - tre;  sim[ch][p1] = uim - tim;
        }
        __syncthreads();
    }
    // forward 3-point C-DFT + store
    for (int i = t; i < Wn; i += TPB) {
        int a = SWZ(i);
        float x0 = sre[0][a], y0 = sim[0][a];
        float x1 = sre[1][a], y1 = sim[1][a];
        float x2 = sre[2][a], y2 = sim[2][a];
        float sx = x1 + x2, sy = y1 + y2, dx = x1 - x2, dy = y1 - y2;
        Fb[i]           = make_float2(x0 + sx, y0 + sy);
        Fb[HWn + i]     = make_float2(x0 - 0.5f * sx + S3 * dy, y0 - 0.5f * sy - S3 * dx);
        Fb[2 * HWn + i] = make_float2(x0 - 0.5f * sx - S3 * dy, y0 - 0.5f * sy + S3 * dx);
    }
}

// ---------------------------------------------------------------------------
// Inverse: 3-point C-inverse fused with inverse W-FFT and |.|/N -> SRabs.
// ---------------------------------------------------------------------------
__global__ __launch_bounds__(TPB) void k_ifft_wc_abs(const float2* __restrict__ F,
                                                     float* __restrict__ SRabs) {
    __shared__ float sre[3][576], sim[3][576], twc[256], tws[256];
    int rb = blockIdx.x;
    int b = rb >> 10, h = rb & 1023;
    const float2* Fb = F + (long long)b * CHWn + (long long)h * Wn;
    float* ob = SRabs + (long long)b * CHWn + (long long)h * Wn;
    int t = threadIdx.x;

    {   float s, c;
        sincospif(2.0f * (float)t / (float)Wn, &s, &c);
        twc[t] = c; tws[t] = s; }
    for (int i = t; i < Wn; i += TPB) {
        float2 z0 = Fb[i], z1 = Fb[HWn + i], z2 = Fb[2 * HWn + i];
        float sx = z1.x + z2.x, sy = z1.y + z2.y;
        float dx = z1.x - z2.x, dy = z1.y - z2.y;
        int j = SWZ(__brev((unsigned)i) >> (32 - 9));
        sre[0][j] = z0.x + sx;                 sim[0][j] = z0.y + sy;
        sre[1][j] = z0.x - 0.5f * sx - S3 * dy; sim[1][j] = z0.y - 0.5f * sy + S3 * dx;
        sre[2][j] = z0.x - 0.5f * sx + S3 * dy; sim[2][j] = z0.y - 0.5f * sy - S3 * dx;
    }
    __syncthreads();
    #pragma unroll
    for (int st = 0; st < 9; st++) {
        int half = 1 << st;
        int blk = t >> st, j = t & (half - 1);
        int pos = (blk << (st + 1)) + j;
        float c = twc[j << (8 - st)], s = tws[j << (8 - st)];
        int p0 = SWZ(pos), p1 = SWZ(pos + half);
        #pragma unroll
        for (int ch = 0; ch < 3; ch++) {
            float ure = sre[ch][p0], uim = sim[ch][p0];
            float vre = sre[ch][p1], vim = sim[ch][p1];
            float tre = vre * c - vim * s, tim = vre * s + vim * c;
            sre[ch][p0] = ure + tre;  sim[ch][p0] = uim + tim;
            sre[ch][p1] = ure - tre;  sim[ch][p1] = uim - tim;
        }
        __syncthreads();
    }
    for (int i = t; i < Wn; i += TPB) {
        int a = SWZ(i);
        #pragma unroll
        for (int ch = 0; ch < 3; ch++) {
            float re = sre[ch][a], im = sim[ch][a];
            ob[ch * HWn + i] = sqrtf(re * re + im * im) * INV_NTOT;
        }
    }
}

// ---------------------------------------------------------------------------
// FFT along H (1024). 8 w-columns per block (64B row chunks), 512 threads,
// LDS float2 tile[1024][9] (77.8KB, 2 blocks/CU).
//  - XCD pairing swizzle: the two blocks sharing each 128B line have bids
//    differing by 8 -> same XCD -> line fetched once from HBM.
//  - Scatter loads rows h = c + 128*d (d = lane group): bit-reversed rows
//    are consecutive -> uniform LDS banks. Writeback uses natural rows.
// INV=0 (fwd): epilogue writes LA = log(|F|+eps).
// INV=1 (inv): prologue applies compose G = exp(LA-AF) * z/|z| before FFT.
// ---------------------------------------------------------------------------
template <int INV>
__global__ __launch_bounds__(512) void k_fft_h(float2* __restrict__ F,
                                               float* __restrict__ LA,
                                               const float* __restrict__ AF) {
    __shared__ float2 tile[1024][9];
    __shared__ float twc[512], tws[512];
    int bid = blockIdx.x;
    int g  = bid & 63;
    int bc = bid >> 6;                 // b*C + c, 0..23
    // pairing: bids g and g+8 -> adjacent 8-col tiles (same 128B line, same XCD)
    int p = g & 7, q3 = (g >> 3) & 1, r = g >> 4;
    int wt = ((p + (r << 3)) << 1) | q3;      // 0..63, bijective
    int w0 = wt << 3;
    float2* base = F + (long long)bc * HWn + w0;
    float* LAp = LA + (long long)bc * HWn + w0;
    const float* AFb = AF + (long long)(bc / 3) * HWn + w0;
    int t = threadIdx.x;

    {   float s, c;
        sincospif((INV ? 2.0f : -2.0f) * (float)t / (float)Hn, &s, &c);
        twc[t] = c; tws[t] = s; }

    int w = t & 7;
    int d = (t >> 3) & 7;
    #pragma unroll
    for (int k = 0; k < 16; k++) {
        int c8 = (t >> 6) + (k << 3);          // wave-uniform, 0..127
        int h = c8 + (d << 7);                 // rows strided by 128
        float2 z = base[(long long)h * Wn + w];
        if (INV) {
            float la = LAp[(long long)h * Wn + w];
            float af = AFb[(long long)h * Wn + w];
            float m = expf(la - af);
            float rr = sqrtf(z.x * z.x + z.y * z.y);
            if (rr > 0.0f) { float sc = m / rr; z.x *= sc; z.y *= sc; }
            else           { z.x = m; z.y = 0.0f; }
        }
        int hj = __brev((unsigned)h) >> (32 - 10);   // consecutive across d
        tile[hj][w] = z;
    }
    __syncthreads();

    for (int st = 0; st < 10; st++) {
        int half = 1 << st;
        #pragma unroll
        for (int qq = 0; qq < 8; qq++) {       // 4096 butterflies / 512 thr
            int q = qq * 512 + t;
            int ww = q & 7;
            int i = q >> 3;                    // 0..511
            int blk = i >> st, j = i & (half - 1);
            int pos = (blk << (st + 1)) + j;
            float c = twc[j << (9 - st)], s = tws[j << (9 - st)];
            float2 u = tile[pos][ww];
            float2 v = tile[pos + half][ww];
            float tre = v.x * c - v.y * s;
            float tim = v.x * s + v.y * c;
            tile[pos][ww]        = make_float2(u.x + tre, u.y + tim);
            tile[pos + half][ww] = make_float2(u.x - tre, u.y - tim);
        }
        __syncthreads();
    }

    #pragma unroll
    for (int k = 0; k < 16; k++) {
        int grp = (t >> 6) + (k << 3);         // 0..127
        int h = (grp << 3) | ((t >> 3) & 7);   // natural consecutive rows
        float2 z = tile[h][w];
        base[(long long)h * Wn + w] = z;
        if (!INV) {
            LAp[(long long)h * Wn + w] =
                logf(sqrtf(z.x * z.x + z.y * z.y) + EPS10);
        }
    }
}

// ---------------------------------------------------------------------------
// 3x3 channel-summed separable conv (zero pad), 128w x 8h tile, float4 I/O.
// GAU=0: box 1/9. GAU=1: gaussian 1/16 + per-block partial sums (no atomics).
// ---------------------------------------------------------------------------
template <int GAU>
__global__ __launch_bounds__(TPB) void k_conv3x3(const float* __restrict__ src,
                                                 float* __restrict__ dst,
                                                 float* __restrict__ part) {
    __shared__ float tile[3][10][140];
    int w0 = blockIdx.x << 7;
    int h0 = blockIdx.y << 3;
    int b  = blockIdx.z;
    int t  = threadIdx.x;

    for (int i = t; i < 1020; i += TPB) {          // 3*10*34 float4 loads
        int c = i / 340, rem = i - c * 340;
        int hh = rem / 34, w4 = rem - hh * 34;
        int h  = h0 + hh - 1;
        int gw = w0 - 4 + (w4 << 2);
        float4 v = make_float4(0.f, 0.f, 0.f, 0.f);
        if ((unsigned)h < (unsigned)Hn && (unsigned)gw <= 508u)
            v = *(const float4*)(src + ((long long)(b * 3 + c)) * HWn +
                                 (long long)h * Wn + gw);
        *(float4*)&tile[c][hh][w4 << 2] = v;
    }
    __syncthreads();

    const float K = GAU ? 2.0f : 1.0f;
    const float norm = GAU ? (1.0f / 16.0f) : (1.0f / 9.0f);
    int hh = t >> 5;
    int wb = (t & 31) << 2;
    float o0 = 0.f, o1 = 0.f, o2 = 0.f, o3 = 0.f;
    #pragma unroll
    for (int c = 0; c < 3; c++)
        #pragma unroll
        for (int dh = 0; dh < 3; dh++) {
            const float* row = &tile[c][hh + dh][3 + wb];
            float a0 = row[0], a1 = row[1], a2 = row[2],
                  a3 = row[3], a4 = row[4], a5 = row[5];
            float vw = (dh == 1) ? K : 1.0f;
            o0 += vw * (a0 + K * a1 + a2);
            o1 += vw * (a1 + K * a2 + a3);
            o2 += vw * (a2 + K * a3 + a4);
            o3 += vw * (a3 + K * a4 + a5);
        }
    o0 *= norm; o1 *= norm; o2 *= norm; o3 *= norm;
    *(float4*)(dst + (long long)b * HWn + (long long)(h0 + hh) * Wn + w0 + wb)
        = make_float4(o0, o1, o2, o3);

    if (GAU) {
        float s = o0 + o1 + o2 + o3;
        #pragma unroll
        for (int o = 32; o > 0; o >>= 1) s += __shfl_down(s, o);
        __shared__ float ls[4];
        if ((t & 63) == 0) ls[t >> 6] = s;
        __syncthreads();
        if (t == 0)
            part[((long long)b << 9) + (blockIdx.y << 2) + blockIdx.x]
                = ls[0] + ls[1] + ls[2] + ls[3];
    }
}

// ---------------------------------------------------------------------------
// Reduce 512 per-block partials per batch -> mean[b].
// ---------------------------------------------------------------------------
__global__ __launch_bounds__(TPB) void k_mean_final(const float* __restrict__ part,
                                                    float* __restrict__ mean) {
    int b = blockIdx.x;
    int t = threadIdx.x;
    float s = part[(b << 9) + t] + part[(b << 9) + 256 + t];
    #pragma unroll
    for (int o = 32; o > 0; o >>= 1) s += __shfl_down(s, o);
    __shared__ float ls[4];
    if ((t & 63) == 0) ls[t >> 6] = s;
    __syncthreads();
    if (t == 0)
        mean[b] = (ls[0] + ls[1] + ls[2] + ls[3]) * (1.0f / (float)HWn);
}

// ---------------------------------------------------------------------------
// out[b,h,o] = b_out[o] + sum_{w,k} thr(SRg[b,(h+k-1)%H,w]) * w_out[o,w,k]
// 64h x 64o tile, 4x4/thread, grid 1024 (4 blocks/CU). A transposed in LDS
// (As[w][row], stride 68): a-reads are broadcast b128+b64, conflict-free.
// ---------------------------------------------------------------------------
__global__ __launch_bounds__(TPB) void k_outgemm(const float* __restrict__ SRg,
                                                 const float* __restrict__ meanv,
                                                 const float* __restrict__ w_out,
                                                 const float* __restrict__ b_out,
                                                 float* __restrict__ out) {
    __shared__ __align__(16) float As[32][68];    // [w][row 0..65]
    __shared__ __align__(16) float Bs[3][32][64];
    int o0 = blockIdx.x << 6;
    int h0 = blockIdx.y << 6;
    int b = blockIdx.z;
    int t = threadIdx.x;
    int to = t & 15, th = t >> 4;
    float meanb = meanv[b];
    const float* srb = SRg + (long long)b * HWn;

    float acc[4][4];
    #pragma unroll
    for (int i = 0; i < 4; i++)
        #pragma unroll
        for (int j = 0; j < 4; j++) acc[i][j] = 0.0f;

    for (int w0 = 0; w0 < Wn; w0 += 32) {
        // A tile: rows h0-1 .. h0+64 (wrap), 32 w cols, thresholded, transposed
        for (int i = t; i < 66 * 32; i += TPB) {
            int r = i >> 5, wc = i & 31;
            int h = (h0 - 1 + r) & (Hn - 1);
            float v = srb[(long long)h * Wn + w0 + wc];
            As[wc][r] = (v > meanb) ? v : 0.0f;
        }
        // B tile: w_out[o][w][k] -> Bs[k][w][oo]
        {
            int oo = t & 63, g = t >> 6;
            const float4* wpv = (const float4*)(w_out +
                (long long)(o0 + oo) * 1536 + (long long)w0 * 3 + g * 24);
            #pragma unroll
            for (int j2 = 0; j2 < 6; j2++) {
                float4 v4 = wpv[j2];
                int mm = j2 * 4;
                Bs[(mm) % 3][g * 8 + (mm) / 3][oo]         = v4.x;
                Bs[(mm + 1) % 3][g * 8 + (mm + 1) / 3][oo] = v4.y;
                Bs[(mm + 2) % 3][g * 8 + (mm + 2) / 3][oo] = v4.z;
                Bs[(mm + 3) % 3][g * 8 + (mm + 3) / 3][oo] = v4.w;
            }
        }
        __syncthreads();
        for (int w = 0; w < 32; w++) {
            float4 a03 = *(const float4*)&As[w][th << 2];
            float2 a45 = *(const float2*)&As[w][(th << 2) + 4];
            float a[6] = {a03.x, a03.y, a03.z, a03.w, a45.x, a45.y};
            #pragma unroll
            for (int k = 0; k < 3; k++) {
                float4 bv = *(const float4*)&Bs[k][w][to << 2];
                #pragma unroll
                for (int i2 = 0; i2 < 4; i2++) {
                    acc[i2][0] += a[i2 + k] * bv.x;
                    acc[i2][1] += a[i2 + k] * bv.y;
                    acc[i2][2] += a[i2 + k] * bv.z;
                    acc[i2][3] += a[i2 + k] * bv.w;
                }
            }
        }
        __syncthreads();
    }

    float4 bias = *(const float4*)&b_out[o0 + (to << 2)];
    #pragma unroll
    for (int i2 = 0; i2 < 4; i2++) {
        int h = h0 + (th << 2) + i2;
        float4 v = make_float4(acc[i2][0] + bias.x, acc[i2][1] + bias.y,
                               acc[i2][2] + bias.z, acc[i2][3] + bias.w);
        *(float4*)&out[((long long)b * Hn + h) * 512 + o0 + (to << 2)] = v;
    }
}

// ---------------------------------------------------------------------------
extern "C" void kernel_launch(void* const* d_in, const int* in_sizes, int n_in,
                              void* d_out, int out_size, void* d_ws, size_t ws_size,
                              hipStream_t stream) {
    (void)in_sizes; (void)n_in; (void)out_size;
    const float* x     = (const float*)d_in[0];
    const float* w_out = (const float*)d_in[1];
    const float* b_out = (const float*)d_in[2];
    float* out = (float*)d_out;

    const size_t CBUF_BYTES = (size_t)Bn * CHWn * sizeof(float2);  // 100663296
    const size_t LA_BYTES   = (size_t)Bn * CHWn * sizeof(float);   //  50331648
    const size_t AF_BYTES   = (size_t)Bn * HWn * sizeof(float);    //  16777216
    const size_t NEED = CBUF_BYTES + LA_BYTES + AF_BYTES + 64 + 4096 * sizeof(float);
    if (ws_size < NEED) return;

    char* ws = (char*)d_ws;
    float2* CBUF = (float2*)ws;
    float*  LA   = (float*)(ws + CBUF_BYTES);
    float*  AF   = (float*)(ws + CBUF_BYTES + LA_BYTES);
    float*  MEAN = (float*)(ws + CBUF_BYTES + LA_BYTES + AF_BYTES);
    float*  PART = (float*)(ws + CBUF_BYTES + LA_BYTES + AF_BYTES + 64);

    // forward: W-FFT + C-DFT fused; H-FFT writes F and LA
    k_fft_wc_fwd<<<Bn * Hn, TPB, 0, stream>>>(x, CBUF);
    k_fft_h<0><<<Bn * Cn * 64, 512, 0, stream>>>(CBUF, LA, nullptr);

    // spectral residual: box conv on LA -> AF
    k_conv3x3<0><<<dim3(4, 128, 8), TPB, 0, stream>>>(LA, AF, nullptr);

    // inverse: compose fused into H-inv load; C-inv + W-inv + abs fused
    k_fft_h<1><<<Bn * Cn * 64, 512, 0, stream>>>(CBUF, LA, AF);
    k_ifft_wc_abs<<<Bn * Hn, TPB, 0, stream>>>(CBUF, LA);   // SRabs -> LA

    // gaussian conv (+partials) -> SRg in AF; mean; output GEMM
    k_conv3x3<1><<<dim3(4, 128, 8), TPB, 0, stream>>>(LA, AF, PART);
    k_mean_final<<<8, TPB, 0, stream>>>(PART, MEAN);
    k_outgemm<<<dim3(8, 16, Bn), TPB, 0, stream>>>(AF, MEAN, w_out, b_out, out);
}